// Round 6
// baseline (606.637 us; speedup 1.0000x reference)
//
#include <hip/hip_runtime.h>
#include <cstdint>
#include <cstddef>

// ---------------------------------------------------------------------------
//   x:    [B=128, T=256, D=1024] fp32
//   Wk:   [1024, 512] per dir    Wr: [128, 512]    bias: [512]
//   xp[dir][t*128+b][512] = x[b,t,:] @ Wk + bias   (bf16, t-major, bias folded)
//   LSTM R6: M=seq / N=gate-dim orientation (as R4/R5) but Wr fragments live
//   in LDS (bf16, swizzled to B-frag layout), re-read each step with
//   conflict-free ds_read_b128. Removes the 64-VGPR loop-invariant live
//   range the compiler refused to keep (R4: remat ~400 VALU/step; R5: pin
//   -> spill). Step floor = LDS BW: 8 waves x 16KB / 128B/cy ~ 1024 cy.
//   x prefetch via explicit address_space(1) loads (vmcnt-only, immune to
//   LITE_BARRIER's lgkmcnt drain).
// ---------------------------------------------------------------------------

typedef __attribute__((ext_vector_type(8))) short short8;
typedef __attribute__((ext_vector_type(4))) float f32x4;
typedef __attribute__((address_space(1))) unsigned int gas_uint;
typedef __attribute__((address_space(3))) unsigned int las_uint;
typedef __attribute__((address_space(1))) const unsigned short as1_us;

__device__ __forceinline__ unsigned short f2b(float f) {
    unsigned int u = __float_as_uint(f);
    u += 0x7FFFu + ((u >> 16) & 1u);          // RNE
    return (unsigned short)(u >> 16);
}
__device__ __forceinline__ float b2f(unsigned short u) {
    return __uint_as_float(((unsigned int)u) << 16);
}
__device__ __forceinline__ float sigmoidf_(float z) { return 1.0f / (1.0f + __expf(-z)); }
__device__ __forceinline__ float tanhf_(float z) {
    float e = __expf(2.0f * z);
    return 1.0f - 2.0f / (e + 1.0f);
}

// workgroup barrier WITHOUT the vmcnt(0) drain __syncthreads would emit:
// LDS ordering only — outstanding global prefetch loads stay in flight.
#define LITE_BARRIER() asm volatile("s_waitcnt lgkmcnt(0)\n\ts_barrier" ::: "memory")

// async global->LDS 16B
__device__ __forceinline__ void async_ld16(const unsigned short* g, unsigned short* l) {
    __builtin_amdgcn_global_load_lds(
        (gas_uint*)(uintptr_t)g,
        (las_uint*)(uintptr_t)(unsigned int)(uintptr_t)l,
        16, 0, 0);
}

// ---------------------------------------------------------------------------
// Kernel 1: x fp32 -> bf16
// ---------------------------------------------------------------------------
__global__ void conv_x(const float* __restrict__ x, unsigned short* __restrict__ xb, int n8) {
    int idx = blockIdx.x * blockDim.x + threadIdx.x;
    int stride = gridDim.x * blockDim.x;
    for (int i = idx; i < n8; i += stride) {
        const float4* p = ((const float4*)x) + (size_t)i * 2;
        float4 a = p[0], b = p[1];
        short8 r;
        r[0] = (short)f2b(a.x); r[1] = (short)f2b(a.y);
        r[2] = (short)f2b(a.z); r[3] = (short)f2b(a.w);
        r[4] = (short)f2b(b.x); r[5] = (short)f2b(b.y);
        r[6] = (short)f2b(b.z); r[7] = (short)f2b(b.w);
        *(((short8*)xb) + i) = r;
    }
}

// ---------------------------------------------------------------------------
// Kernel 2: transpose + convert Wk [1024][512] -> Wk_t [512][1024] bf16
// ---------------------------------------------------------------------------
__global__ void conv_wk(const float* __restrict__ wf, const float* __restrict__ wb,
                        unsigned short* __restrict__ wt) {
    int dir = blockIdx.y;
    const float* w = dir ? wb : wf;
    int id = blockIdx.x * blockDim.x + threadIdx.x;
    int g = id >> 10, d = id & 1023;
    wt[(size_t)dir * 524288 + id] = f2b(w[d * 512 + g]);
}

// ---------------------------------------------------------------------------
// Kernel 3: GEMM xp = A[32768,1024] @ Wk_t^T + bias -> bf16 t-major [t*128+b][512]
// (unchanged: 128x128 tile, BK=64, global_load_lds w=16, XOR swizzle)
// ---------------------------------------------------------------------------
__global__ __launch_bounds__(256, 2) void gemm_xp(
    const unsigned short* __restrict__ A,
    const unsigned short* __restrict__ Wt,
    const float* __restrict__ bf_, const float* __restrict__ bb_,
    unsigned short* __restrict__ XP)
{
    __shared__ unsigned short As[128 * 64];
    __shared__ unsigned short Bs[128 * 64];

    const int tid  = threadIdx.x;
    const int dir  = blockIdx.z;
    const int tm   = blockIdx.x;             // 0..255
    const int tn   = blockIdx.y;             // 0..3
    const int w    = tid >> 6;
    const int lane = tid & 63;
    const int lanelo = lane & 15;
    const int quad = lane >> 4;
    const int wm = w & 1, wn = w >> 1;

    const unsigned short* Bmat = Wt + (size_t)dir * 524288;
    const float* bias = dir ? bb_ : bf_;
    unsigned short* out = XP + (size_t)dir * 16777216;

    const unsigned short* ga[4];
    const unsigned short* gb[4];
    unsigned short* la[4];
    unsigned short* lb[4];
#pragma unroll
    for (int c = 0; c < 4; ++c) {
        int p = c * 256 + tid;
        int row = p >> 3;
        int lc = (p & 7) ^ (row & 7);
        ga[c] = A    + (size_t)(tm * 128 + row) * 1024 + lc * 8;
        gb[c] = Bmat + (size_t)(tn * 128 + row) * 1024 + lc * 8;
        int ub = (c * 256 + (tid & ~63)) * 8;
        la[c] = As + ub;
        lb[c] = Bs + ub;
    }

    f32x4 acc[4][4];
#pragma unroll
    for (int i = 0; i < 4; i++)
#pragma unroll
        for (int j = 0; j < 4; j++) acc[i][j] = (f32x4){0.f, 0.f, 0.f, 0.f};

    for (int kt = 0; kt < 16; ++kt) {
        __syncthreads();
#pragma unroll
        for (int c = 0; c < 4; ++c) {
            async_ld16(ga[c] + kt * 64, la[c]);
            async_ld16(gb[c] + kt * 64, lb[c]);
        }
        __syncthreads();
#pragma unroll
        for (int ks = 0; ks < 2; ++ks) {
            short8 af[4], bfr[4];
#pragma unroll
            for (int i = 0; i < 4; ++i) {
                int row = wm * 64 + i * 16 + lanelo;
                af[i] = *(const short8*)(As + row * 64 + (((ks * 4 + quad) ^ (row & 7)) * 8));
            }
#pragma unroll
            for (int j = 0; j < 4; ++j) {
                int row = wn * 64 + j * 16 + lanelo;
                bfr[j] = *(const short8*)(Bs + row * 64 + (((ks * 4 + quad) ^ (row & 7)) * 8));
            }
#pragma unroll
            for (int i = 0; i < 4; ++i)
#pragma unroll
                for (int j = 0; j < 4; ++j)
                    acc[i][j] = __builtin_amdgcn_mfma_f32_16x16x32_bf16(af[i], bfr[j], acc[i][j], 0, 0, 0);
        }
    }

    float biasv[4];
#pragma unroll
    for (int j = 0; j < 4; ++j)
        biasv[j] = bias[tn * 128 + wn * 64 + j * 16 + lanelo];

#pragma unroll
    for (int i = 0; i < 4; ++i) {
#pragma unroll
        for (int r = 0; r < 4; ++r) {
            int gr = tm * 128 + wm * 64 + i * 16 + quad * 4 + r;   // = b*256 + t
            int bb = gr >> 8, tt = gr & 255;
            size_t orow = (size_t)(tt * 128 + bb) * 512;
#pragma unroll
            for (int j = 0; j < 4; ++j) {
                int col = tn * 128 + wn * 64 + j * 16 + lanelo;
                out[orow + col] = f2b(acc[i][j][r] + biasv[j]);
            }
        }
    }
}

// ---------------------------------------------------------------------------
// Kernel 4: LSTM recurrence. 128 blocks x 512 thr; block = (dir, seq-pair).
// M=seq orientation:  A = h [2 x 128] (rows 0,1 valid), B = Wr [128 x 512].
// Wave w: 4 gate-tiles (N = g*128 + [16w,16w+16)) x 4 k-steps = 16 MFMAs.
// Wr lives in LDS as bf16, swizzled so each fragment is one conflict-free
// ds_read_b128:  elem (k, col) at byte  col*256 + ((2k) ^ ((col&15)<<4)).
// Fragment (g,ks), lane (lanelo,quad), elem j = Wr[ks*32+quad*8+j][g*128+dim]
//   -> byte (g*128+dim)*256 + ((ks*64+quad*16) ^ (lanelo<<4)) + 2j.
// Quad-0 lanes hold all 4 gates of dim (16w+lanelo) in MFMA output regs ->
// activation in-lane, h written as 2 b16 LDS stores, one lite barrier/step.
// ---------------------------------------------------------------------------
__global__ __launch_bounds__(512, 2) void lstm_rec(
    const unsigned short* __restrict__ XP,    // [2][256*128][512] bf16, bias folded
    const float* __restrict__ Wfr, const float* __restrict__ Wbr,
    float* __restrict__ Hout)                 // [2][128][128]
{
    __shared__ unsigned short wr_lds[512 * 128];   // 128 KB swizzled bf16 Wr
    __shared__ unsigned short h_lds[2][2][128];    // [buf][seq][dim], 1 KB

    const int tid    = threadIdx.x;
    const int w      = tid >> 6;              // 0..7
    const int lane   = tid & 63;
    const int lanelo = lane & 15;
    const int quad   = lane >> 4;
    const int dir    = blockIdx.x >> 6;
    const int b0     = (blockIdx.x & 63) * 2;
    const int dim    = w * 16 + lanelo;       // 0..127

    const float* Wr = dir ? Wbr : Wfr;
    const unsigned short* xp = XP + (size_t)dir * 16777216;

    // ---- one-time: fill wr_lds (thread owns one gate-col, 16 b128 stores) ----
    {
        const int col = tid;                  // 0..511
        for (int kb = 0; kb < 16; ++kb) {
            short8 f;
#pragma unroll
            for (int j = 0; j < 8; ++j)
                f[j] = (short)f2b(Wr[(size_t)(kb * 8 + j) * 512 + col]);
            int boff = col * 256 + ((kb * 16) ^ ((col & 15) << 4));
            *(short8*)((char*)wr_lds + boff) = f;
        }
        if (tid < 256) ((unsigned short*)h_lds)[tid] = 0;   // zero h buffer 0
    }
    __syncthreads();

    // precomputed element offsets (ushort units) for the 16 fragment reads
    int woff[4][4];
#pragma unroll
    for (int g = 0; g < 4; ++g)
#pragma unroll
        for (int ks = 0; ks < 4; ++ks)
            woff[g][ks] = ((g * 128 + dim) * 256 +
                           ((ks * 64 + quad * 16) ^ (lanelo << 4))) >> 1;

    // A-fragments of h; only lanes with lanelo<2 ever load real rows.
    short8 hfrag[4];
    const short8 hz = (short8){0, 0, 0, 0, 0, 0, 0, 0};
#pragma unroll
    for (int ks = 0; ks < 4; ++ks) hfrag[ks] = hz;

    float c0v = 0.f, c1v = 0.f, h0v = 0.f, h1v = 0.f;

    // x prefetch: explicit address_space(1) loads (global_load_ushort,
    // vmcnt-only). Quads duplicate quad-0 addresses (broadcast, no cost).
    const ptrdiff_t xstep = dir ? -65536 : 65536;       // elements per t
    const unsigned short* xb_ =
        xp + (size_t)(dir ? 255 : 0) * 65536 + (size_t)b0 * 512 + dim;

    unsigned int xA[8], xB[8];
    {
        const as1_us* xg = (const as1_us*)(uintptr_t)xb_;
#pragma unroll
        for (int s = 0; s < 2; ++s)
#pragma unroll
            for (int g = 0; g < 4; ++g) xA[s * 4 + g] = xg[s * 512 + g * 128];
        xb_ += xstep;
        xg = (const as1_us*)(uintptr_t)xb_;
#pragma unroll
        for (int s = 0; s < 2; ++s)
#pragma unroll
            for (int g = 0; g < 4; ++g) xB[s * 4 + g] = xg[s * 512 + g * 128];
        xb_ += xstep;
    }

    LITE_BARRIER();                           // h_lds[0] zeros visible (redundant w/ syncthreads, cheap)

    const f32x4 kZ = (f32x4){0.f, 0.f, 0.f, 0.f};

#define LSTM_STEP(XC, CUR, NXT)                                                  \
    {                                                                            \
        /* consume x loaded 2 steps ago; reissue prefetch into same regs */      \
        float xv[8];                                                             \
        _Pragma("unroll")                                                        \
        for (int q = 0; q < 8; ++q) xv[q] = b2f((unsigned short)XC[q]);          \
        {                                                                        \
            const as1_us* xg = (const as1_us*)(uintptr_t)xb_;                    \
            _Pragma("unroll")                                                    \
            for (int s = 0; s < 2; ++s)                                          \
                _Pragma("unroll")                                                \
                for (int g = 0; g < 4; ++g) XC[s * 4 + g] = xg[s * 512 + g * 128]; \
            xb_ += xstep;                                                        \
        }                                                                        \
        /* masked A-frag read: only rows 0,1 are real */                         \
        if (lanelo < 2) {                                                        \
            _Pragma("unroll")                                                    \
            for (int ks = 0; ks < 4; ++ks)                                       \
                hfrag[ks] = *(const short8*)(&h_lds[CUR][lanelo][ks * 32 + quad * 8]); \
        }                                                                        \
        /* Wr fragments from LDS (conflict-free b128) + 4 indep MFMA chains */   \
        short8 wv[4][4];                                                         \
        _Pragma("unroll")                                                        \
        for (int g = 0; g < 4; ++g)                                              \
            _Pragma("unroll")                                                    \
            for (int ks = 0; ks < 4; ++ks)                                       \
                wv[g][ks] = *(const short8*)(wr_lds + woff[g][ks]);              \
        f32x4 z0 = __builtin_amdgcn_mfma_f32_16x16x32_bf16(hfrag[0], wv[0][0], kZ, 0, 0, 0); \
        f32x4 z1 = __builtin_amdgcn_mfma_f32_16x16x32_bf16(hfrag[0], wv[1][0], kZ, 0, 0, 0); \
        f32x4 z2 = __builtin_amdgcn_mfma_f32_16x16x32_bf16(hfrag[0], wv[2][0], kZ, 0, 0, 0); \
        f32x4 z3 = __builtin_amdgcn_mfma_f32_16x16x32_bf16(hfrag[0], wv[3][0], kZ, 0, 0, 0); \
        _Pragma("unroll")                                                        \
        for (int ks = 1; ks < 4; ++ks) {                                         \
            z0 = __builtin_amdgcn_mfma_f32_16x16x32_bf16(hfrag[ks], wv[0][ks], z0, 0, 0, 0); \
            z1 = __builtin_amdgcn_mfma_f32_16x16x32_bf16(hfrag[ks], wv[1][ks], z1, 0, 0, 0); \
            z2 = __builtin_amdgcn_mfma_f32_16x16x32_bf16(hfrag[ks], wv[2][ks], z2, 0, 0, 0); \
            z3 = __builtin_amdgcn_mfma_f32_16x16x32_bf16(hfrag[ks], wv[3][ks], z3, 0, 0, 0); \
        }                                                                        \
        /* activation: quad-0 lanes own (dim, both seqs); all gates local */     \
        if (quad == 0) {                                                         \
            float zi0 = z0[0] + xv[0], zf0 = z1[0] + xv[1];                      \
            float zg0 = z2[0] + xv[2], zo0 = z3[0] + xv[3];                      \
            float zi1 = z0[1] + xv[4], zf1 = z1[1] + xv[5];                      \
            float zg1 = z2[1] + xv[6], zo1 = z3[1] + xv[7];                      \
            float i0 = sigmoidf_(zi0), f0 = sigmoidf_(zf0);                      \
            float g0 = tanhf_(zg0),    o0 = sigmoidf_(zo0);                      \
            c0v = f0 * c0v + i0 * g0;                                            \
            h0v = o0 * tanhf_(c0v);                                              \
            float i1 = sigmoidf_(zi1), f1 = sigmoidf_(zf1);                      \
            float g1 = tanhf_(zg1),    o1 = sigmoidf_(zo1);                      \
            c1v = f1 * c1v + i1 * g1;                                            \
            h1v = o1 * tanhf_(c1v);                                              \
            h_lds[NXT][0][dim] = f2b(h0v);                                       \
            h_lds[NXT][1][dim] = f2b(h1v);                                       \
        }                                                                        \
        LITE_BARRIER();                                                          \
    }

    for (int t = 0; t < 256; t += 2) {
        LSTM_STEP(xA, 0, 1)
        LSTM_STEP(xB, 1, 0)
    }
#undef LSTM_STEP

    if (quad == 0) {
        Hout[(size_t)(dir * 128 + b0) * 128 + dim]     = h0v;
        Hout[(size_t)(dir * 128 + b0 + 1) * 128 + dim] = h1v;
    }
}

// ---------------------------------------------------------------------------
// Kernel 5: MLP head
// ---------------------------------------------------------------------------
__global__ void mlp_head(const float* __restrict__ Hout,
                         const float* __restrict__ W1, const float* __restrict__ b1,
                         const float* __restrict__ W2, const float* __restrict__ b2,
                         float* __restrict__ out)
{
    __shared__ float y1[32];
    int b = blockIdx.x;
    int j = threadIdx.x;
    const float* hf = Hout + (size_t)b * 128;
    const float* hb = Hout + (size_t)(128 + b) * 128;
    if (j < 32) {
        float acc = b1[j];
        for (int k = 0; k < 128; ++k) acc += hf[k] * W1[k * 32 + j];
        for (int k = 0; k < 128; ++k) acc += hb[k] * W1[(128 + k) * 32 + j];
        y1[j] = fmaxf(acc, 0.0f);
    }
    __syncthreads();
    if (j < 2) {
        float z = b2[j];
        for (int k = 0; k < 32; ++k) z += y1[k] * W2[k * 2 + j];
        out[b * 2 + j] = 1.0f / (1.0f + __expf(-z));
    }
}

// ---------------------------------------------------------------------------
extern "C" void kernel_launch(void* const* d_in, const int* in_sizes, int n_in,
                              void* d_out, int out_size, void* d_ws, size_t ws_size,
                              hipStream_t stream) {
    const float* x    = (const float*)d_in[0];
    const float* Wf_k = (const float*)d_in[1];
    const float* Wf_r = (const float*)d_in[2];
    const float* bf   = (const float*)d_in[3];
    const float* Wb_k = (const float*)d_in[4];
    const float* Wb_r = (const float*)d_in[5];
    const float* bb   = (const float*)d_in[6];
    const float* W1   = (const float*)d_in[7];
    const float* b1   = (const float*)d_in[8];
    const float* W2   = (const float*)d_in[9];
    const float* b2   = (const float*)d_in[10];
    float* out = (float*)d_out;

    char* ws = (char*)d_ws;
    const size_t OFF_XB   = 0;                        // 67,108,864 B
    const size_t OFF_WT   = 67108864;                 //  2,097,152 B
    const size_t OFF_HOUT = OFF_WT + 2097152;         //    131,072 B
    const size_t OFF_XP   = OFF_HOUT + 131072;        // 67,108,864 B (bf16)

    unsigned short* xb  = (unsigned short*)(ws + OFF_XB);
    unsigned short* wt  = (unsigned short*)(ws + OFF_WT);
    float*          ho  = (float*)(ws + OFF_HOUT);
    unsigned short* xpb = (unsigned short*)(ws + OFF_XP);

    conv_x<<<dim3(2048), dim3(256), 0, stream>>>(x, xb, 33554432 / 8);
    conv_wk<<<dim3(2048, 2), dim3(256), 0, stream>>>(Wf_k, Wb_k, wt);
    gemm_xp<<<dim3(256, 4, 2), dim3(256), 0, stream>>>(xb, wt, bf, bb, xpb);
    lstm_rec<<<dim3(128), dim3(512), 0, stream>>>(xpb, Wf_r, Wb_r, ho);
    mlp_head<<<dim3(128), dim3(64), 0, stream>>>(ho, W1, b1, W2, b2, out);
}

// Round 7
// 466.277 us; speedup vs baseline: 1.3010x; 1.3010x over previous
//
#include <hip/hip_runtime.h>
#include <cstdint>
#include <cstddef>

// ---------------------------------------------------------------------------
//   x:    [B=128, T=256, D=1024] fp32
//   Wk:   [1024, 512] per dir    Wr: [128, 512]    bias: [512]
//   xp[dir][t*128+b][512] = x[b,t,:] @ Wk + bias   (bf16, t-major, bias folded)
//   LSTM R7: R4 structure (M=seq / N=gate-dim, 8 waves, wrf in regs/AGPRs,
//   in-lane activation, 1 lite barrier/step) with the REAL fix:
//   - all fp32 divisions in sigmoid/tanh replaced by v_rcp_f32
//     (__builtin_amdgcn_rcpf). Without fast-math each 1/x was compiling to
//     the ~11-instr exact-division sequence; 10 of them per wave per step
//     was the "mystery VALU" (R6 falsified the remat theory: wrf-in-LDS
//     removed any remat possibility yet VALUBusy barely moved).
//   - x prefetch deepened to 4 steps (4 rotating reg buffers).
// ---------------------------------------------------------------------------

typedef __attribute__((ext_vector_type(8))) short short8;
typedef __attribute__((ext_vector_type(4))) float f32x4;
typedef __attribute__((address_space(1))) unsigned int gas_uint;
typedef __attribute__((address_space(3))) unsigned int las_uint;
typedef __attribute__((address_space(1))) const unsigned short as1_us;

__device__ __forceinline__ unsigned short f2b(float f) {
    unsigned int u = __float_as_uint(f);
    u += 0x7FFFu + ((u >> 16) & 1u);          // RNE
    return (unsigned short)(u >> 16);
}
__device__ __forceinline__ float b2f(unsigned short u) {
    return __uint_as_float(((unsigned int)u) << 16);
}
// fast activations: v_rcp_f32 instead of exact fp32 division (~1 ulp; far
// below the bf16 noise floor of this pipeline).
__device__ __forceinline__ float rcp_(float x) { return __builtin_amdgcn_rcpf(x); }
__device__ __forceinline__ float sigmoidf_(float z) { return rcp_(1.0f + __expf(-z)); }
__device__ __forceinline__ float tanhf_(float z) {
    float e = __expf(2.0f * z);
    return 1.0f - 2.0f * rcp_(e + 1.0f);
}

// workgroup barrier WITHOUT the vmcnt(0) drain __syncthreads would emit:
// LDS ordering only — outstanding global prefetch loads stay in flight.
#define LITE_BARRIER() asm volatile("s_waitcnt lgkmcnt(0)\n\ts_barrier" ::: "memory")

// async global->LDS 16B
__device__ __forceinline__ void async_ld16(const unsigned short* g, unsigned short* l) {
    __builtin_amdgcn_global_load_lds(
        (gas_uint*)(uintptr_t)g,
        (las_uint*)(uintptr_t)(unsigned int)(uintptr_t)l,
        16, 0, 0);
}

// ---------------------------------------------------------------------------
// Kernel 1: x fp32 -> bf16
// ---------------------------------------------------------------------------
__global__ void conv_x(const float* __restrict__ x, unsigned short* __restrict__ xb, int n8) {
    int idx = blockIdx.x * blockDim.x + threadIdx.x;
    int stride = gridDim.x * blockDim.x;
    for (int i = idx; i < n8; i += stride) {
        const float4* p = ((const float4*)x) + (size_t)i * 2;
        float4 a = p[0], b = p[1];
        short8 r;
        r[0] = (short)f2b(a.x); r[1] = (short)f2b(a.y);
        r[2] = (short)f2b(a.z); r[3] = (short)f2b(a.w);
        r[4] = (short)f2b(b.x); r[5] = (short)f2b(b.y);
        r[6] = (short)f2b(b.z); r[7] = (short)f2b(b.w);
        *(((short8*)xb) + i) = r;
    }
}

// ---------------------------------------------------------------------------
// Kernel 2: transpose + convert Wk [1024][512] -> Wk_t [512][1024] bf16
// ---------------------------------------------------------------------------
__global__ void conv_wk(const float* __restrict__ wf, const float* __restrict__ wb,
                        unsigned short* __restrict__ wt) {
    int dir = blockIdx.y;
    const float* w = dir ? wb : wf;
    int id = blockIdx.x * blockDim.x + threadIdx.x;
    int g = id >> 10, d = id & 1023;
    wt[(size_t)dir * 524288 + id] = f2b(w[d * 512 + g]);
}

// ---------------------------------------------------------------------------
// Kernel 3: GEMM xp = A[32768,1024] @ Wk_t^T + bias -> bf16 t-major [t*128+b][512]
// (unchanged: 128x128 tile, BK=64, global_load_lds w=16, XOR swizzle)
// ---------------------------------------------------------------------------
__global__ __launch_bounds__(256, 2) void gemm_xp(
    const unsigned short* __restrict__ A,
    const unsigned short* __restrict__ Wt,
    const float* __restrict__ bf_, const float* __restrict__ bb_,
    unsigned short* __restrict__ XP)
{
    __shared__ unsigned short As[128 * 64];
    __shared__ unsigned short Bs[128 * 64];

    const int tid  = threadIdx.x;
    const int dir  = blockIdx.z;
    const int tm   = blockIdx.x;             // 0..255
    const int tn   = blockIdx.y;             // 0..3
    const int w    = tid >> 6;
    const int lane = tid & 63;
    const int lanelo = lane & 15;
    const int quad = lane >> 4;
    const int wm = w & 1, wn = w >> 1;

    const unsigned short* Bmat = Wt + (size_t)dir * 524288;
    const float* bias = dir ? bb_ : bf_;
    unsigned short* out = XP + (size_t)dir * 16777216;

    const unsigned short* ga[4];
    const unsigned short* gb[4];
    unsigned short* la[4];
    unsigned short* lb[4];
#pragma unroll
    for (int c = 0; c < 4; ++c) {
        int p = c * 256 + tid;
        int row = p >> 3;
        int lc = (p & 7) ^ (row & 7);
        ga[c] = A    + (size_t)(tm * 128 + row) * 1024 + lc * 8;
        gb[c] = Bmat + (size_t)(tn * 128 + row) * 1024 + lc * 8;
        int ub = (c * 256 + (tid & ~63)) * 8;
        la[c] = As + ub;
        lb[c] = Bs + ub;
    }

    f32x4 acc[4][4];
#pragma unroll
    for (int i = 0; i < 4; i++)
#pragma unroll
        for (int j = 0; j < 4; j++) acc[i][j] = (f32x4){0.f, 0.f, 0.f, 0.f};

    for (int kt = 0; kt < 16; ++kt) {
        __syncthreads();
#pragma unroll
        for (int c = 0; c < 4; ++c) {
            async_ld16(ga[c] + kt * 64, la[c]);
            async_ld16(gb[c] + kt * 64, lb[c]);
        }
        __syncthreads();
#pragma unroll
        for (int ks = 0; ks < 2; ++ks) {
            short8 af[4], bfr[4];
#pragma unroll
            for (int i = 0; i < 4; ++i) {
                int row = wm * 64 + i * 16 + lanelo;
                af[i] = *(const short8*)(As + row * 64 + (((ks * 4 + quad) ^ (row & 7)) * 8));
            }
#pragma unroll
            for (int j = 0; j < 4; ++j) {
                int row = wn * 64 + j * 16 + lanelo;
                bfr[j] = *(const short8*)(Bs + row * 64 + (((ks * 4 + quad) ^ (row & 7)) * 8));
            }
#pragma unroll
            for (int i = 0; i < 4; ++i)
#pragma unroll
                for (int j = 0; j < 4; ++j)
                    acc[i][j] = __builtin_amdgcn_mfma_f32_16x16x32_bf16(af[i], bfr[j], acc[i][j], 0, 0, 0);
        }
    }

    float biasv[4];
#pragma unroll
    for (int j = 0; j < 4; ++j)
        biasv[j] = bias[tn * 128 + wn * 64 + j * 16 + lanelo];

#pragma unroll
    for (int i = 0; i < 4; ++i) {
#pragma unroll
        for (int r = 0; r < 4; ++r) {
            int gr = tm * 128 + wm * 64 + i * 16 + quad * 4 + r;   // = b*256 + t
            int bb = gr >> 8, tt = gr & 255;
            size_t orow = (size_t)(tt * 128 + bb) * 512;
#pragma unroll
            for (int j = 0; j < 4; ++j) {
                int col = tn * 128 + wn * 64 + j * 16 + lanelo;
                out[orow + col] = f2b(acc[i][j][r] + biasv[j]);
            }
        }
    }
}

// ---------------------------------------------------------------------------
// Kernel 4: LSTM recurrence. 128 blocks x 512 thr; block = (dir, seq-pair).
// M=seq orientation:  A = h [2 x 128] (rows 0,1 valid), B = Wr [128 x 512].
// Wave w: 4 gate-tiles (N = g*128 + [16w,16w+16)) x 4 k-steps = 16 MFMAs.
// Quad-0 lanes hold z for all 4 gates of dim (16w+lanelo) in MFMA output
// regs -> activation in-lane (rcp-fast), h written as 2 b16 LDS stores.
// One lite barrier per step. x prefetch depth 4.
// ---------------------------------------------------------------------------
__global__ __launch_bounds__(512, 2) void lstm_rec(
    const unsigned short* __restrict__ XP,    // [2][256*128][512] bf16, bias folded
    const float* __restrict__ Wfr, const float* __restrict__ Wbr,
    float* __restrict__ Hout)                 // [2][128][128]
{
    __shared__ unsigned short h_lds[2][2][128]; // [buf][seq][dim]

    const int tid    = threadIdx.x;
    const int w      = tid >> 6;              // 0..7
    const int lane   = tid & 63;
    const int lanelo = lane & 15;
    const int quad   = lane >> 4;
    const int dir    = blockIdx.x >> 6;
    const int b0     = (blockIdx.x & 63) * 2;
    const int dim    = w * 16 + lanelo;       // 0..127

    const float* Wr = dir ? Wbr : Wfr;
    const unsigned short* xp = XP + (size_t)dir * 16777216;

    // --- one-time B-fragments: wrf[g][ks][j] = Wr[ks*32+quad*8+j][g*128+dim]
    //     (fp32 -> bf16 in-register; 16 frags; compiler may park in AGPRs) ---
    short8 wrf[4][4];
#pragma unroll
    for (int g = 0; g < 4; ++g)
#pragma unroll
        for (int ks = 0; ks < 4; ++ks) {
            short8 f;
#pragma unroll
            for (int j = 0; j < 8; ++j)
                f[j] = (short)f2b(Wr[(size_t)(ks * 32 + quad * 8 + j) * 512 + g * 128 + dim]);
            wrf[g][ks] = f;
        }

    if (tid < 256) ((unsigned short*)h_lds)[tid] = 0;   // zero h buffer 0

    // A-fragments of h; only lanes with lanelo<2 ever load real rows.
    short8 hfrag[4];
    const short8 hz = (short8){0, 0, 0, 0, 0, 0, 0, 0};
#pragma unroll
    for (int ks = 0; ks < 4; ++ks) hfrag[ks] = hz;

    float c0v = 0.f, c1v = 0.f, h0v = 0.f, h1v = 0.f;

    // x prefetch: explicit address_space(1) loads (vmcnt-only, immune to the
    // lgkmcnt drain in LITE_BARRIER). Depth 4: consume buf, re-load for t+4.
    const ptrdiff_t xstep = dir ? -65536 : 65536;       // elements per t
    const unsigned short* xb_ =
        xp + (size_t)(dir ? 255 : 0) * 65536 + (size_t)b0 * 512 + dim;

    unsigned int xA[8], xB[8], xC[8], xD[8];

#define XLOAD(BUF)                                                               \
    {                                                                            \
        const as1_us* xg = (const as1_us*)(uintptr_t)xb_;                        \
        _Pragma("unroll")                                                        \
        for (int s = 0; s < 2; ++s)                                              \
            _Pragma("unroll")                                                    \
            for (int g = 0; g < 4; ++g) BUF[s * 4 + g] = xg[s * 512 + g * 128];  \
        xb_ += xstep;                                                            \
    }

    XLOAD(xA)   // t=0
    XLOAD(xB)   // t=1
    XLOAD(xC)   // t=2
    XLOAD(xD)   // t=3
    // overshoot past t=255 stays inside the XP allocation (reads the other
    // direction's region; values unused).

    LITE_BARRIER();                           // h_lds[0] zeros visible

    const f32x4 kZ = (f32x4){0.f, 0.f, 0.f, 0.f};

#define LSTM_STEP(XC_, CUR, NXT)                                                 \
    {                                                                            \
        /* consume x loaded 4 steps ago (long arrived); reissue for t+4 */       \
        float xv[8];                                                             \
        _Pragma("unroll")                                                        \
        for (int q = 0; q < 8; ++q) xv[q] = b2f((unsigned short)XC_[q]);         \
        XLOAD(XC_)                                                               \
        /* masked A-frag read: only rows 0,1 are real */                         \
        if (lanelo < 2) {                                                        \
            _Pragma("unroll")                                                    \
            for (int ks = 0; ks < 4; ++ks)                                       \
                hfrag[ks] = *(const short8*)(&h_lds[CUR][lanelo][ks * 32 + quad * 8]); \
        }                                                                        \
        /* 16 MFMAs: 4 independent gate chains, depth 4 */                       \
        f32x4 z0 = __builtin_amdgcn_mfma_f32_16x16x32_bf16(hfrag[0], wrf[0][0], kZ, 0, 0, 0); \
        f32x4 z1 = __builtin_amdgcn_mfma_f32_16x16x32_bf16(hfrag[0], wrf[1][0], kZ, 0, 0, 0); \
        f32x4 z2 = __builtin_amdgcn_mfma_f32_16x16x32_bf16(hfrag[0], wrf[2][0], kZ, 0, 0, 0); \
        f32x4 z3 = __builtin_amdgcn_mfma_f32_16x16x32_bf16(hfrag[0], wrf[3][0], kZ, 0, 0, 0); \
        _Pragma("unroll")                                                        \
        for (int ks = 1; ks < 4; ++ks) {                                         \
            z0 = __builtin_amdgcn_mfma_f32_16x16x32_bf16(hfrag[ks], wrf[0][ks], z0, 0, 0, 0); \
            z1 = __builtin_amdgcn_mfma_f32_16x16x32_bf16(hfrag[ks], wrf[1][ks], z1, 0, 0, 0); \
            z2 = __builtin_amdgcn_mfma_f32_16x16x32_bf16(hfrag[ks], wrf[2][ks], z2, 0, 0, 0); \
            z3 = __builtin_amdgcn_mfma_f32_16x16x32_bf16(hfrag[ks], wrf[3][ks], z3, 0, 0, 0); \
        }                                                                        \
        /* activation: quad-0 lanes own (dim, both seqs); all gates local */     \
        if (quad == 0) {                                                         \
            float zi0 = z0[0] + xv[0], zf0 = z1[0] + xv[1];                      \
            float zg0 = z2[0] + xv[2], zo0 = z3[0] + xv[3];                      \
            float zi1 = z0[1] + xv[4], zf1 = z1[1] + xv[5];                      \
            float zg1 = z2[1] + xv[6], zo1 = z3[1] + xv[7];                      \
            float i0 = sigmoidf_(zi0), f0 = sigmoidf_(zf0);                      \
            float g0 = tanhf_(zg0),    o0 = sigmoidf_(zo0);                      \
            c0v = f0 * c0v + i0 * g0;                                            \
            h0v = o0 * tanhf_(c0v);                                              \
            float i1 = sigmoidf_(zi1), f1 = sigmoidf_(zf1);                      \
            float g1 = tanhf_(zg1),    o1 = sigmoidf_(zo1);                      \
            c1v = f1 * c1v + i1 * g1;                                            \
            h1v = o1 * tanhf_(c1v);                                              \
            h_lds[NXT][0][dim] = f2b(h0v);                                       \
            h_lds[NXT][1][dim] = f2b(h1v);                                       \
        }                                                                        \
        LITE_BARRIER();                                                          \
    }

    for (int t = 0; t < 256; t += 4) {
        LSTM_STEP(xA, 0, 1)
        LSTM_STEP(xB, 1, 0)
        LSTM_STEP(xC, 0, 1)
        LSTM_STEP(xD, 1, 0)
    }
#undef LSTM_STEP
#undef XLOAD

    if (quad == 0) {
        Hout[(size_t)(dir * 128 + b0) * 128 + dim]     = h0v;
        Hout[(size_t)(dir * 128 + b0 + 1) * 128 + dim] = h1v;
    }
}

// ---------------------------------------------------------------------------
// Kernel 5: MLP head
// ---------------------------------------------------------------------------
__global__ void mlp_head(const float* __restrict__ Hout,
                         const float* __restrict__ W1, const float* __restrict__ b1,
                         const float* __restrict__ W2, const float* __restrict__ b2,
                         float* __restrict__ out)
{
    __shared__ float y1[32];
    int b = blockIdx.x;
    int j = threadIdx.x;
    const float* hf = Hout + (size_t)b * 128;
    const float* hb = Hout + (size_t)(128 + b) * 128;
    if (j < 32) {
        float acc = b1[j];
        for (int k = 0; k < 128; ++k) acc += hf[k] * W1[k * 32 + j];
        for (int k = 0; k < 128; ++k) acc += hb[k] * W1[(128 + k) * 32 + j];
        y1[j] = fmaxf(acc, 0.0f);
    }
    __syncthreads();
    if (j < 2) {
        float z = b2[j];
        for (int k = 0; k < 32; ++k) z += y1[k] * W2[k * 2 + j];
        out[b * 2 + j] = 1.0f / (1.0f + __expf(-z));
    }
}

// ---------------------------------------------------------------------------
extern "C" void kernel_launch(void* const* d_in, const int* in_sizes, int n_in,
                              void* d_out, int out_size, void* d_ws, size_t ws_size,
                              hipStream_t stream) {
    const float* x    = (const float*)d_in[0];
    const float* Wf_k = (const float*)d_in[1];
    const float* Wf_r = (const float*)d_in[2];
    const float* bf   = (const float*)d_in[3];
    const float* Wb_k = (const float*)d_in[4];
    const float* Wb_r = (const float*)d_in[5];
    const float* bb   = (const float*)d_in[6];
    const float* W1   = (const float*)d_in[7];
    const float* b1   = (const float*)d_in[8];
    const float* W2   = (const float*)d_in[9];
    const float* b2   = (const float*)d_in[10];
    float* out = (float*)d_out;

    char* ws = (char*)d_ws;
    const size_t OFF_XB   = 0;                        // 67,108,864 B
    const size_t OFF_WT   = 67108864;                 //  2,097,152 B
    const size_t OFF_HOUT = OFF_WT + 2097152;         //    131,072 B
    const size_t OFF_XP   = OFF_HOUT + 131072;        // 67,108,864 B (bf16)

    unsigned short* xb  = (unsigned short*)(ws + OFF_XB);
    unsigned short* wt  = (unsigned short*)(ws + OFF_WT);
    float*          ho  = (float*)(ws + OFF_HOUT);
    unsigned short* xpb = (unsigned short*)(ws + OFF_XP);

    conv_x<<<dim3(2048), dim3(256), 0, stream>>>(x, xb, 33554432 / 8);
    conv_wk<<<dim3(2048, 2), dim3(256), 0, stream>>>(Wf_k, Wb_k, wt);
    gemm_xp<<<dim3(256, 4, 2), dim3(256), 0, stream>>>(xb, wt, bf, bb, xpb);
    lstm_rec<<<dim3(128), dim3(512), 0, stream>>>(xpb, Wf_r, Wb_r, ho);
    mlp_head<<<dim3(128), dim3(64), 0, stream>>>(ho, W1, b1, W2, b2, out);
}

// Round 8
// 423.122 us; speedup vs baseline: 1.4337x; 1.1020x over previous
//
#include <hip/hip_runtime.h>
#include <cstdint>
#include <cstddef>

// ---------------------------------------------------------------------------
//   x:    [B=128, T=256, D=1024] fp32
//   Wk:   [1024, 512] per dir    Wr: [128, 512]    bias: [512]
//   xp[dir][t*128+b][512] = x[b,t,:] @ Wk + bias   (bf16, t-major, bias folded)
//   LSTM R8: ONE seq per block, 256 blocks (all CUs). Rationale: the per-step
//   MFMA cost (128 x 16x16x32 per CU = ~620cy) is constant in seqs/block
//   (M-rows are free), but activation/exchange cost scales with seqs/block.
//   1 seq halves phase-2 vs R7's 2 seqs at zero MFMA cost, using the idle
//   half of the chip. Structure otherwise = R7 (M=seq / N=gate-dim, 8 waves,
//   rcp-fast activations, in-lane activation, 1 lite barrier/step, x depth-4).
// ---------------------------------------------------------------------------

typedef __attribute__((ext_vector_type(8))) short short8;
typedef __attribute__((ext_vector_type(4))) float f32x4;
typedef __attribute__((address_space(1))) unsigned int gas_uint;
typedef __attribute__((address_space(3))) unsigned int las_uint;
typedef __attribute__((address_space(1))) const unsigned short as1_us;

__device__ __forceinline__ unsigned short f2b(float f) {
    unsigned int u = __float_as_uint(f);
    u += 0x7FFFu + ((u >> 16) & 1u);          // RNE
    return (unsigned short)(u >> 16);
}
__device__ __forceinline__ float b2f(unsigned short u) {
    return __uint_as_float(((unsigned int)u) << 16);
}
// fast activations: v_rcp_f32 instead of exact fp32 division (~1 ulp)
__device__ __forceinline__ float rcp_(float x) { return __builtin_amdgcn_rcpf(x); }
__device__ __forceinline__ float sigmoidf_(float z) { return rcp_(1.0f + __expf(-z)); }
__device__ __forceinline__ float tanhf_(float z) {
    float e = __expf(2.0f * z);
    return 1.0f - 2.0f * rcp_(e + 1.0f);
}

// workgroup barrier WITHOUT the vmcnt(0) drain __syncthreads would emit:
// LDS ordering only — outstanding global prefetch loads stay in flight.
#define LITE_BARRIER() asm volatile("s_waitcnt lgkmcnt(0)\n\ts_barrier" ::: "memory")

// async global->LDS 16B
__device__ __forceinline__ void async_ld16(const unsigned short* g, unsigned short* l) {
    __builtin_amdgcn_global_load_lds(
        (gas_uint*)(uintptr_t)g,
        (las_uint*)(uintptr_t)(unsigned int)(uintptr_t)l,
        16, 0, 0);
}

// ---------------------------------------------------------------------------
// Kernel 1: x fp32 -> bf16
// ---------------------------------------------------------------------------
__global__ void conv_x(const float* __restrict__ x, unsigned short* __restrict__ xb, int n8) {
    int idx = blockIdx.x * blockDim.x + threadIdx.x;
    int stride = gridDim.x * blockDim.x;
    for (int i = idx; i < n8; i += stride) {
        const float4* p = ((const float4*)x) + (size_t)i * 2;
        float4 a = p[0], b = p[1];
        short8 r;
        r[0] = (short)f2b(a.x); r[1] = (short)f2b(a.y);
        r[2] = (short)f2b(a.z); r[3] = (short)f2b(a.w);
        r[4] = (short)f2b(b.x); r[5] = (short)f2b(b.y);
        r[6] = (short)f2b(b.z); r[7] = (short)f2b(b.w);
        *(((short8*)xb) + i) = r;
    }
}

// ---------------------------------------------------------------------------
// Kernel 2: transpose + convert Wk [1024][512] -> Wk_t [512][1024] bf16
// ---------------------------------------------------------------------------
__global__ void conv_wk(const float* __restrict__ wf, const float* __restrict__ wb,
                        unsigned short* __restrict__ wt) {
    int dir = blockIdx.y;
    const float* w = dir ? wb : wf;
    int id = blockIdx.x * blockDim.x + threadIdx.x;
    int g = id >> 10, d = id & 1023;
    wt[(size_t)dir * 524288 + id] = f2b(w[d * 512 + g]);
}

// ---------------------------------------------------------------------------
// Kernel 3: GEMM xp = A[32768,1024] @ Wk_t^T + bias -> bf16 t-major [t*128+b][512]
// (unchanged: 128x128 tile, BK=64, global_load_lds w=16, XOR swizzle)
// ---------------------------------------------------------------------------
__global__ __launch_bounds__(256, 2) void gemm_xp(
    const unsigned short* __restrict__ A,
    const unsigned short* __restrict__ Wt,
    const float* __restrict__ bf_, const float* __restrict__ bb_,
    unsigned short* __restrict__ XP)
{
    __shared__ unsigned short As[128 * 64];
    __shared__ unsigned short Bs[128 * 64];

    const int tid  = threadIdx.x;
    const int dir  = blockIdx.z;
    const int tm   = blockIdx.x;             // 0..255
    const int tn   = blockIdx.y;             // 0..3
    const int w    = tid >> 6;
    const int lane = tid & 63;
    const int lanelo = lane & 15;
    const int quad = lane >> 4;
    const int wm = w & 1, wn = w >> 1;

    const unsigned short* Bmat = Wt + (size_t)dir * 524288;
    const float* bias = dir ? bb_ : bf_;
    unsigned short* out = XP + (size_t)dir * 16777216;

    const unsigned short* ga[4];
    const unsigned short* gb[4];
    unsigned short* la[4];
    unsigned short* lb[4];
#pragma unroll
    for (int c = 0; c < 4; ++c) {
        int p = c * 256 + tid;
        int row = p >> 3;
        int lc = (p & 7) ^ (row & 7);
        ga[c] = A    + (size_t)(tm * 128 + row) * 1024 + lc * 8;
        gb[c] = Bmat + (size_t)(tn * 128 + row) * 1024 + lc * 8;
        int ub = (c * 256 + (tid & ~63)) * 8;
        la[c] = As + ub;
        lb[c] = Bs + ub;
    }

    f32x4 acc[4][4];
#pragma unroll
    for (int i = 0; i < 4; i++)
#pragma unroll
        for (int j = 0; j < 4; j++) acc[i][j] = (f32x4){0.f, 0.f, 0.f, 0.f};

    for (int kt = 0; kt < 16; ++kt) {
        __syncthreads();
#pragma unroll
        for (int c = 0; c < 4; ++c) {
            async_ld16(ga[c] + kt * 64, la[c]);
            async_ld16(gb[c] + kt * 64, lb[c]);
        }
        __syncthreads();
#pragma unroll
        for (int ks = 0; ks < 2; ++ks) {
            short8 af[4], bfr[4];
#pragma unroll
            for (int i = 0; i < 4; ++i) {
                int row = wm * 64 + i * 16 + lanelo;
                af[i] = *(const short8*)(As + row * 64 + (((ks * 4 + quad) ^ (row & 7)) * 8));
            }
#pragma unroll
            for (int j = 0; j < 4; ++j) {
                int row = wn * 64 + j * 16 + lanelo;
                bfr[j] = *(const short8*)(Bs + row * 64 + (((ks * 4 + quad) ^ (row & 7)) * 8));
            }
#pragma unroll
            for (int i = 0; i < 4; ++i)
#pragma unroll
                for (int j = 0; j < 4; ++j)
                    acc[i][j] = __builtin_amdgcn_mfma_f32_16x16x32_bf16(af[i], bfr[j], acc[i][j], 0, 0, 0);
        }
    }

    float biasv[4];
#pragma unroll
    for (int j = 0; j < 4; ++j)
        biasv[j] = bias[tn * 128 + wn * 64 + j * 16 + lanelo];

#pragma unroll
    for (int i = 0; i < 4; ++i) {
#pragma unroll
        for (int r = 0; r < 4; ++r) {
            int gr = tm * 128 + wm * 64 + i * 16 + quad * 4 + r;   // = b*256 + t
            int bb = gr >> 8, tt = gr & 255;
            size_t orow = (size_t)(tt * 128 + bb) * 512;
#pragma unroll
            for (int j = 0; j < 4; ++j) {
                int col = tn * 128 + wn * 64 + j * 16 + lanelo;
                out[orow + col] = f2b(acc[i][j][r] + biasv[j]);
            }
        }
    }
}

// ---------------------------------------------------------------------------
// Kernel 4: LSTM recurrence. 256 blocks x 512 thr; block = (dir, seq).
// M=seq orientation (row 0 only real):  A = h [1 x 128], B = Wr [128 x 512].
// Wave w: 4 gate-tiles (N = g*128 + [16w,16w+16)) x 4 k-steps = 16 MFMAs.
// Quad-0 lanes hold z for all 4 gates of dim (16w+lanelo) in MFMA output
// regs -> activation in-lane (rcp-fast), h written as 1 b16 LDS store.
// One lite barrier per step. x prefetch depth 4.
// ---------------------------------------------------------------------------
__global__ __launch_bounds__(512, 2) void lstm_rec(
    const unsigned short* __restrict__ XP,    // [2][256*128][512] bf16, bias folded
    const float* __restrict__ Wfr, const float* __restrict__ Wbr,
    float* __restrict__ Hout)                 // [2][128][128]
{
    __shared__ unsigned short h_lds[2][128];  // [buf][dim]

    const int tid    = threadIdx.x;
    const int w      = tid >> 6;              // 0..7
    const int lane   = tid & 63;
    const int lanelo = lane & 15;
    const int quad   = lane >> 4;
    const int dir    = blockIdx.x >> 7;
    const int seq    = blockIdx.x & 127;
    const int dim    = w * 16 + lanelo;       // 0..127

    const float* Wr = dir ? Wbr : Wfr;
    const unsigned short* xp = XP + (size_t)dir * 16777216;

    // --- one-time B-fragments: wrf[g][ks][j] = Wr[ks*32+quad*8+j][g*128+dim]
    short8 wrf[4][4];
#pragma unroll
    for (int g = 0; g < 4; ++g)
#pragma unroll
        for (int ks = 0; ks < 4; ++ks) {
            short8 f;
#pragma unroll
            for (int j = 0; j < 8; ++j)
                f[j] = (short)f2b(Wr[(size_t)(ks * 32 + quad * 8 + j) * 512 + g * 128 + dim]);
            wrf[g][ks] = f;
        }

    if (tid < 128) ((unsigned short*)h_lds)[tid] = 0;   // zero h buffer 0

    // A-fragment of h; only row 0 (lanelo==0 lanes) is real.
    short8 hfrag[4];
    const short8 hz = (short8){0, 0, 0, 0, 0, 0, 0, 0};
#pragma unroll
    for (int ks = 0; ks < 4; ++ks) hfrag[ks] = hz;

    float cv = 0.f, hv = 0.f;

    // x prefetch: explicit address_space(1) loads (vmcnt-only, immune to the
    // lgkmcnt drain in LITE_BARRIER). Depth 4: consume buf, re-load for t+4.
    const ptrdiff_t xstep = dir ? -65536 : 65536;       // elements per t
    const unsigned short* xb_ =
        xp + (size_t)(dir ? 255 : 0) * 65536 + (size_t)seq * 512 + dim;

    unsigned int xA[4], xB[4], xC[4], xD[4];

#define XLOAD(BUF)                                                               \
    {                                                                            \
        const as1_us* xg = (const as1_us*)(uintptr_t)xb_;                        \
        _Pragma("unroll")                                                        \
        for (int g = 0; g < 4; ++g) BUF[g] = xg[g * 128];                        \
        xb_ += xstep;                                                            \
    }

    XLOAD(xA)   // t=0
    XLOAD(xB)   // t=1
    XLOAD(xC)   // t=2
    XLOAD(xD)   // t=3
    // overshoot past the sequence end stays inside the XP allocation
    // (reads the other direction's region; values unused).

    LITE_BARRIER();                           // h_lds[0] zeros visible

    const f32x4 kZ = (f32x4){0.f, 0.f, 0.f, 0.f};

#define LSTM_STEP(XC_, CUR, NXT)                                                 \
    {                                                                            \
        /* consume x loaded 4 steps ago (long arrived); reissue for t+4 */       \
        float xv0 = b2f((unsigned short)XC_[0]);                                 \
        float xv1 = b2f((unsigned short)XC_[1]);                                 \
        float xv2 = b2f((unsigned short)XC_[2]);                                 \
        float xv3 = b2f((unsigned short)XC_[3]);                                 \
        XLOAD(XC_)                                                               \
        /* masked A-frag read: only row 0 is real */                             \
        if (lanelo == 0) {                                                       \
            _Pragma("unroll")                                                    \
            for (int ks = 0; ks < 4; ++ks)                                       \
                hfrag[ks] = *(const short8*)(&h_lds[CUR][ks * 32 + quad * 8]);   \
        }                                                                        \
        /* 16 MFMAs: 4 independent gate chains, depth 4 */                       \
        f32x4 z0 = __builtin_amdgcn_mfma_f32_16x16x32_bf16(hfrag[0], wrf[0][0], kZ, 0, 0, 0); \
        f32x4 z1 = __builtin_amdgcn_mfma_f32_16x16x32_bf16(hfrag[0], wrf[1][0], kZ, 0, 0, 0); \
        f32x4 z2 = __builtin_amdgcn_mfma_f32_16x16x32_bf16(hfrag[0], wrf[2][0], kZ, 0, 0, 0); \
        f32x4 z3 = __builtin_amdgcn_mfma_f32_16x16x32_bf16(hfrag[0], wrf[3][0], kZ, 0, 0, 0); \
        _Pragma("unroll")                                                        \
        for (int ks = 1; ks < 4; ++ks) {                                         \
            z0 = __builtin_amdgcn_mfma_f32_16x16x32_bf16(hfrag[ks], wrf[0][ks], z0, 0, 0, 0); \
            z1 = __builtin_amdgcn_mfma_f32_16x16x32_bf16(hfrag[ks], wrf[1][ks], z1, 0, 0, 0); \
            z2 = __builtin_amdgcn_mfma_f32_16x16x32_bf16(hfrag[ks], wrf[2][ks], z2, 0, 0, 0); \
            z3 = __builtin_amdgcn_mfma_f32_16x16x32_bf16(hfrag[ks], wrf[3][ks], z3, 0, 0, 0); \
        }                                                                        \
        /* activation: quad-0 lanes own (dim); all gates in-lane */              \
        if (quad == 0) {                                                         \
            float zi = z0[0] + xv0, zf = z1[0] + xv1;                            \
            float zg = z2[0] + xv2, zo = z3[0] + xv3;                            \
            float iv = sigmoidf_(zi), fv = sigmoidf_(zf);                        \
            float gv = tanhf_(zg),    ov = sigmoidf_(zo);                        \
            cv = fv * cv + iv * gv;                                              \
            hv = ov * tanhf_(cv);                                                \
            h_lds[NXT][dim] = f2b(hv);                                           \
        }                                                                        \
        LITE_BARRIER();                                                          \
    }

    for (int t = 0; t < 256; t += 4) {
        LSTM_STEP(xA, 0, 1)
        LSTM_STEP(xB, 1, 0)
        LSTM_STEP(xC, 0, 1)
        LSTM_STEP(xD, 1, 0)
    }
#undef LSTM_STEP
#undef XLOAD

    if (quad == 0)
        Hout[(size_t)(dir * 128 + seq) * 128 + dim] = hv;
}

// ---------------------------------------------------------------------------
// Kernel 5: MLP head
// ---------------------------------------------------------------------------
__global__ void mlp_head(const float* __restrict__ Hout,
                         const float* __restrict__ W1, const float* __restrict__ b1,
                         const float* __restrict__ W2, const float* __restrict__ b2,
                         float* __restrict__ out)
{
    __shared__ float y1[32];
    int b = blockIdx.x;
    int j = threadIdx.x;
    const float* hf = Hout + (size_t)b * 128;
    const float* hb = Hout + (size_t)(128 + b) * 128;
    if (j < 32) {
        float acc = b1[j];
        for (int k = 0; k < 128; ++k) acc += hf[k] * W1[k * 32 + j];
        for (int k = 0; k < 128; ++k) acc += hb[k] * W1[(128 + k) * 32 + j];
        y1[j] = fmaxf(acc, 0.0f);
    }
    __syncthreads();
    if (j < 2) {
        float z = b2[j];
        for (int k = 0; k < 32; ++k) z += y1[k] * W2[k * 2 + j];
        out[b * 2 + j] = 1.0f / (1.0f + __expf(-z));
    }
}

// ---------------------------------------------------------------------------
extern "C" void kernel_launch(void* const* d_in, const int* in_sizes, int n_in,
                              void* d_out, int out_size, void* d_ws, size_t ws_size,
                              hipStream_t stream) {
    const float* x    = (const float*)d_in[0];
    const float* Wf_k = (const float*)d_in[1];
    const float* Wf_r = (const float*)d_in[2];
    const float* bf   = (const float*)d_in[3];
    const float* Wb_k = (const float*)d_in[4];
    const float* Wb_r = (const float*)d_in[5];
    const float* bb   = (const float*)d_in[6];
    const float* W1   = (const float*)d_in[7];
    const float* b1   = (const float*)d_in[8];
    const float* W2   = (const float*)d_in[9];
    const float* b2   = (const float*)d_in[10];
    float* out = (float*)d_out;

    char* ws = (char*)d_ws;
    const size_t OFF_XB   = 0;                        // 67,108,864 B
    const size_t OFF_WT   = 67108864;                 //  2,097,152 B
    const size_t OFF_HOUT = OFF_WT + 2097152;         //    131,072 B
    const size_t OFF_XP   = OFF_HOUT + 131072;        // 67,108,864 B (bf16)

    unsigned short* xb  = (unsigned short*)(ws + OFF_XB);
    unsigned short* wt  = (unsigned short*)(ws + OFF_WT);
    float*          ho  = (float*)(ws + OFF_HOUT);
    unsigned short* xpb = (unsigned short*)(ws + OFF_XP);

    conv_x<<<dim3(2048), dim3(256), 0, stream>>>(x, xb, 33554432 / 8);
    conv_wk<<<dim3(2048, 2), dim3(256), 0, stream>>>(Wf_k, Wb_k, wt);
    gemm_xp<<<dim3(256, 4, 2), dim3(256), 0, stream>>>(xb, wt, bf, bb, xpb);
    lstm_rec<<<dim3(256), dim3(512), 0, stream>>>(xpb, Wf_r, Wb_r, ho);
    mlp_head<<<dim3(128), dim3(64), 0, stream>>>(ho, W1, b1, W2, b2, out);
}

// Round 9
// 421.519 us; speedup vs baseline: 1.4392x; 1.0038x over previous
//
#include <hip/hip_runtime.h>
#include <cstdint>
#include <cstddef>

// ---------------------------------------------------------------------------
//   x:    [B=128, T=256, D=1024] fp32
//   Wk:   [1024, 512] per dir    Wr: [128, 512]    bias: [512]
//   xp[dir][t*128+b][512] = x[b,t,:] @ Wk + bias   (bf16, t-major, bias folded)
//   R9: gemm_xp gets an XCD-aware grid remap: each XCD runs all 8 (tn,dir)
//   combos of a tm consecutively -> A-tile read from HBM once, reused 8x
//   from XCD L2 (B panels 2MB + A tile 256KB < 4MB L2). lstm_rec: replicated
//   h A-frags (uniform broadcast LDS reads, no divergent branch; numerically
//   identical). lstm structure otherwise frozen at R8 (133us, matched model).
// ---------------------------------------------------------------------------

typedef __attribute__((ext_vector_type(8))) short short8;
typedef __attribute__((ext_vector_type(4))) float f32x4;
typedef __attribute__((address_space(1))) unsigned int gas_uint;
typedef __attribute__((address_space(3))) unsigned int las_uint;
typedef __attribute__((address_space(1))) const unsigned short as1_us;

__device__ __forceinline__ unsigned short f2b(float f) {
    unsigned int u = __float_as_uint(f);
    u += 0x7FFFu + ((u >> 16) & 1u);          // RNE
    return (unsigned short)(u >> 16);
}
__device__ __forceinline__ float b2f(unsigned short u) {
    return __uint_as_float(((unsigned int)u) << 16);
}
// fast activations: v_rcp_f32 instead of exact fp32 division (~1 ulp)
__device__ __forceinline__ float rcp_(float x) { return __builtin_amdgcn_rcpf(x); }
__device__ __forceinline__ float sigmoidf_(float z) { return rcp_(1.0f + __expf(-z)); }
__device__ __forceinline__ float tanhf_(float z) {
    float e = __expf(2.0f * z);
    return 1.0f - 2.0f * rcp_(e + 1.0f);
}

// workgroup barrier WITHOUT the vmcnt(0) drain __syncthreads would emit:
// LDS ordering only — outstanding global prefetch loads stay in flight.
#define LITE_BARRIER() asm volatile("s_waitcnt lgkmcnt(0)\n\ts_barrier" ::: "memory")

// async global->LDS 16B
__device__ __forceinline__ void async_ld16(const unsigned short* g, unsigned short* l) {
    __builtin_amdgcn_global_load_lds(
        (gas_uint*)(uintptr_t)g,
        (las_uint*)(uintptr_t)(unsigned int)(uintptr_t)l,
        16, 0, 0);
}

// ---------------------------------------------------------------------------
// Kernel 1: x fp32 -> bf16
// ---------------------------------------------------------------------------
__global__ void conv_x(const float* __restrict__ x, unsigned short* __restrict__ xb, int n8) {
    int idx = blockIdx.x * blockDim.x + threadIdx.x;
    int stride = gridDim.x * blockDim.x;
    for (int i = idx; i < n8; i += stride) {
        const float4* p = ((const float4*)x) + (size_t)i * 2;
        float4 a = p[0], b = p[1];
        short8 r;
        r[0] = (short)f2b(a.x); r[1] = (short)f2b(a.y);
        r[2] = (short)f2b(a.z); r[3] = (short)f2b(a.w);
        r[4] = (short)f2b(b.x); r[5] = (short)f2b(b.y);
        r[6] = (short)f2b(b.z); r[7] = (short)f2b(b.w);
        *(((short8*)xb) + i) = r;
    }
}

// ---------------------------------------------------------------------------
// Kernel 2: transpose + convert Wk [1024][512] -> Wk_t [512][1024] bf16
// ---------------------------------------------------------------------------
__global__ void conv_wk(const float* __restrict__ wf, const float* __restrict__ wb,
                        unsigned short* __restrict__ wt) {
    int dir = blockIdx.y;
    const float* w = dir ? wb : wf;
    int id = blockIdx.x * blockDim.x + threadIdx.x;
    int g = id >> 10, d = id & 1023;
    wt[(size_t)dir * 524288 + id] = f2b(w[d * 512 + g]);
}

// ---------------------------------------------------------------------------
// Kernel 3: GEMM xp = A[32768,1024] @ Wk_t^T + bias -> bf16 t-major [t*128+b][512]
// 128x128 tile, BK=64, global_load_lds w=16, XOR swizzle.
// R9: XCD-aware remap. Dispatch id round-robins XCDs (id%8); per XCD the
// work order is (tn,dir) fastest, tm slowest -> one A-tile is used by 8
// consecutive blocks on the SAME XCD (A 256KB + all-B 2MB < 4MB L2), so A
// is fetched from HBM once instead of 8x.
// ---------------------------------------------------------------------------
__global__ __launch_bounds__(256, 2) void gemm_xp(
    const unsigned short* __restrict__ A,
    const unsigned short* __restrict__ Wt,
    const float* __restrict__ bf_, const float* __restrict__ bb_,
    unsigned short* __restrict__ XP)
{
    __shared__ unsigned short As[128 * 64];
    __shared__ unsigned short Bs[128 * 64];

    const int tid  = threadIdx.x;

    // ---- XCD-aware decode (bijective: 2048 = 8 xcd * 256 steps) ----
    const int flat = blockIdx.x + 256 * (blockIdx.y + 4 * blockIdx.z);
    const int xcd  = flat & 7;
    const int p    = flat >> 3;
    const int tn   = p & 3;                  // fastest on an XCD
    const int dir  = (p >> 2) & 1;
    const int tm   = xcd * 32 + (p >> 3);    // 32 tms per XCD

    const int w    = tid >> 6;
    const int lane = tid & 63;
    const int lanelo = lane & 15;
    const int quad = lane >> 4;
    const int wm = w & 1, wn = w >> 1;

    const unsigned short* Bmat = Wt + (size_t)dir * 524288;
    const float* bias = dir ? bb_ : bf_;
    unsigned short* out = XP + (size_t)dir * 16777216;

    const unsigned short* ga[4];
    const unsigned short* gb[4];
    unsigned short* la[4];
    unsigned short* lb[4];
#pragma unroll
    for (int c = 0; c < 4; ++c) {
        int p2 = c * 256 + tid;
        int row = p2 >> 3;
        int lc = (p2 & 7) ^ (row & 7);
        ga[c] = A    + (size_t)(tm * 128 + row) * 1024 + lc * 8;
        gb[c] = Bmat + (size_t)(tn * 128 + row) * 1024 + lc * 8;
        int ub = (c * 256 + (tid & ~63)) * 8;
        la[c] = As + ub;
        lb[c] = Bs + ub;
    }

    f32x4 acc[4][4];
#pragma unroll
    for (int i = 0; i < 4; i++)
#pragma unroll
        for (int j = 0; j < 4; j++) acc[i][j] = (f32x4){0.f, 0.f, 0.f, 0.f};

    for (int kt = 0; kt < 16; ++kt) {
        __syncthreads();
#pragma unroll
        for (int c = 0; c < 4; ++c) {
            async_ld16(ga[c] + kt * 64, la[c]);
            async_ld16(gb[c] + kt * 64, lb[c]);
        }
        __syncthreads();
#pragma unroll
        for (int ks = 0; ks < 2; ++ks) {
            short8 af[4], bfr[4];
#pragma unroll
            for (int i = 0; i < 4; ++i) {
                int row = wm * 64 + i * 16 + lanelo;
                af[i] = *(const short8*)(As + row * 64 + (((ks * 4 + quad) ^ (row & 7)) * 8));
            }
#pragma unroll
            for (int j = 0; j < 4; ++j) {
                int row = wn * 64 + j * 16 + lanelo;
                bfr[j] = *(const short8*)(Bs + row * 64 + (((ks * 4 + quad) ^ (row & 7)) * 8));
            }
#pragma unroll
            for (int i = 0; i < 4; ++i)
#pragma unroll
                for (int j = 0; j < 4; ++j)
                    acc[i][j] = __builtin_amdgcn_mfma_f32_16x16x32_bf16(af[i], bfr[j], acc[i][j], 0, 0, 0);
        }
    }

    float biasv[4];
#pragma unroll
    for (int j = 0; j < 4; ++j)
        biasv[j] = bias[tn * 128 + wn * 64 + j * 16 + lanelo];

#pragma unroll
    for (int i = 0; i < 4; ++i) {
#pragma unroll
        for (int r = 0; r < 4; ++r) {
            int gr = tm * 128 + wm * 64 + i * 16 + quad * 4 + r;   // = b*256 + t
            int bb = gr >> 8, tt = gr & 255;
            size_t orow = (size_t)(tt * 128 + bb) * 512;
#pragma unroll
            for (int j = 0; j < 4; ++j) {
                int col = tn * 128 + wn * 64 + j * 16 + lanelo;
                out[orow + col] = f2b(acc[i][j][r] + biasv[j]);
            }
        }
    }
}

// ---------------------------------------------------------------------------
// Kernel 4: LSTM recurrence. 256 blocks x 512 thr; block = (dir, seq).
// M=seq orientation with REPLICATED h: every A-row = h, so A-frag reads are
// wave-uniform per quad (LDS broadcast, no divergent branch); row-0 output
// is numerically identical to R8. Wave w: 4 gate-tiles x 4 k-steps = 16
// MFMAs (4 indep chains, depth 4, same accumulation order as R8).
// Quad-0 lanes hold z for all 4 gates of dim (16w+lanelo) -> activation
// in-lane (rcp-fast), h written as 1 b16 LDS store. One lite barrier/step.
// x prefetch depth 4 via address_space(1) loads (vmcnt-only).
// ---------------------------------------------------------------------------
__global__ __launch_bounds__(512, 2) void lstm_rec(
    const unsigned short* __restrict__ XP,    // [2][256*128][512] bf16, bias folded
    const float* __restrict__ Wfr, const float* __restrict__ Wbr,
    float* __restrict__ Hout)                 // [2][128][128]
{
    __shared__ unsigned short h_lds[2][128];  // [buf][dim]

    const int tid    = threadIdx.x;
    const int w      = tid >> 6;              // 0..7
    const int lane   = tid & 63;
    const int lanelo = lane & 15;
    const int quad   = lane >> 4;
    const int dir    = blockIdx.x >> 7;
    const int seq    = blockIdx.x & 127;
    const int dim    = w * 16 + lanelo;       // 0..127

    const float* Wr = dir ? Wbr : Wfr;
    const unsigned short* xp = XP + (size_t)dir * 16777216;

    // --- one-time B-fragments: wrf[g][ks][j] = Wr[ks*32+quad*8+j][g*128+dim]
    short8 wrf[4][4];
#pragma unroll
    for (int g = 0; g < 4; ++g)
#pragma unroll
        for (int ks = 0; ks < 4; ++ks) {
            short8 f;
#pragma unroll
            for (int j = 0; j < 8; ++j)
                f[j] = (short)f2b(Wr[(size_t)(ks * 32 + quad * 8 + j) * 512 + g * 128 + dim]);
            wrf[g][ks] = f;
        }

    if (tid < 128) ((unsigned short*)h_lds)[tid] = 0;   // zero h buffer 0

    float cv = 0.f, hv = 0.f;

    // x prefetch: explicit address_space(1) loads (vmcnt-only, immune to the
    // lgkmcnt drain in LITE_BARRIER). Depth 4: consume buf, re-load for t+4.
    const ptrdiff_t xstep = dir ? -65536 : 65536;       // elements per t
    const unsigned short* xb_ =
        xp + (size_t)(dir ? 255 : 0) * 65536 + (size_t)seq * 512 + dim;

    unsigned int xA[4], xB[4], xC[4], xD[4];

#define XLOAD(BUF)                                                               \
    {                                                                            \
        const as1_us* xg = (const as1_us*)(uintptr_t)xb_;                        \
        _Pragma("unroll")                                                        \
        for (int g = 0; g < 4; ++g) BUF[g] = xg[g * 128];                        \
        xb_ += xstep;                                                            \
    }

    XLOAD(xA)   // t=0
    XLOAD(xB)   // t=1
    XLOAD(xC)   // t=2
    XLOAD(xD)   // t=3
    // overshoot past the sequence end stays inside the XP allocation
    // (reads the other direction's region; values unused).

    LITE_BARRIER();                           // h_lds[0] zeros visible

    const f32x4 kZ = (f32x4){0.f, 0.f, 0.f, 0.f};

#define LSTM_STEP(XC_, CUR, NXT)                                                 \
    {                                                                            \
        /* consume x loaded 4 steps ago (long arrived); reissue for t+4 */       \
        float xv0 = b2f((unsigned short)XC_[0]);                                 \
        float xv1 = b2f((unsigned short)XC_[1]);                                 \
        float xv2 = b2f((unsigned short)XC_[2]);                                 \
        float xv3 = b2f((unsigned short)XC_[3]);                                 \
        XLOAD(XC_)                                                               \
        /* replicated-h A-frags: uniform per quad -> LDS broadcast, no branch */ \
        short8 hfrag[4];                                                         \
        _Pragma("unroll")                                                        \
        for (int ks = 0; ks < 4; ++ks)                                           \
            hfrag[ks] = *(const short8*)(&h_lds[CUR][ks * 32 + quad * 8]);       \
        /* 16 MFMAs: 4 independent gate chains, depth 4 (same order as R8) */    \
        f32x4 z0 = __builtin_amdgcn_mfma_f32_16x16x32_bf16(hfrag[0], wrf[0][0], kZ, 0, 0, 0); \
        f32x4 z1 = __builtin_amdgcn_mfma_f32_16x16x32_bf16(hfrag[0], wrf[1][0], kZ, 0, 0, 0); \
        f32x4 z2 = __builtin_amdgcn_mfma_f32_16x16x32_bf16(hfrag[0], wrf[2][0], kZ, 0, 0, 0); \
        f32x4 z3 = __builtin_amdgcn_mfma_f32_16x16x32_bf16(hfrag[0], wrf[3][0], kZ, 0, 0, 0); \
        _Pragma("unroll")                                                        \
        for (int ks = 1; ks < 4; ++ks) {                                         \
            z0 = __builtin_amdgcn_mfma_f32_16x16x32_bf16(hfrag[ks], wrf[0][ks], z0, 0, 0, 0); \
            z1 = __builtin_amdgcn_mfma_f32_16x16x32_bf16(hfrag[ks], wrf[1][ks], z1, 0, 0, 0); \
            z2 = __builtin_amdgcn_mfma_f32_16x16x32_bf16(hfrag[ks], wrf[2][ks], z2, 0, 0, 0); \
            z3 = __builtin_amdgcn_mfma_f32_16x16x32_bf16(hfrag[ks], wrf[3][ks], z3, 0, 0, 0); \
        }                                                                        \
        /* activation: quad-0 lanes own (dim); all gates in-lane */              \
        if (quad == 0) {                                                         \
            float zi = z0[0] + xv0, zf = z1[0] + xv1;                            \
            float zg = z2[0] + xv2, zo = z3[0] + xv3;                            \
            float iv = sigmoidf_(zi), fv = sigmoidf_(zf);                        \
            float gv = tanhf_(zg),    ov = sigmoidf_(zo);                        \
            cv = fv * cv + iv * gv;                                              \
            hv = ov * tanhf_(cv);                                                \
            h_lds[NXT][dim] = f2b(hv);                                           \
        }                                                                        \
        LITE_BARRIER();                                                          \
    }

    for (int t = 0; t < 256; t += 4) {
        LSTM_STEP(xA, 0, 1)
        LSTM_STEP(xB, 1, 0)
        LSTM_STEP(xC, 0, 1)
        LSTM_STEP(xD, 1, 0)
    }
#undef LSTM_STEP
#undef XLOAD

    if (quad == 0)
        Hout[(size_t)(dir * 128 + seq) * 128 + dim] = hv;
}

// ---------------------------------------------------------------------------
// Kernel 5: MLP head
// ---------------------------------------------------------------------------
__global__ void mlp_head(const float* __restrict__ Hout,
                         const float* __restrict__ W1, const float* __restrict__ b1,
                         const float* __restrict__ W2, const float* __restrict__ b2,
                         float* __restrict__ out)
{
    __shared__ float y1[32];
    int b = blockIdx.x;
    int j = threadIdx.x;
    const float* hf = Hout + (size_t)b * 128;
    const float* hb = Hout + (size_t)(128 + b) * 128;
    if (j < 32) {
        float acc = b1[j];
        for (int k = 0; k < 128; ++k) acc += hf[k] * W1[k * 32 + j];
        for (int k = 0; k < 128; ++k) acc += hb[k] * W1[(128 + k) * 32 + j];
        y1[j] = fmaxf(acc, 0.0f);
    }
    __syncthreads();
    if (j < 2) {
        float z = b2[j];
        for (int k = 0; k < 32; ++k) z += y1[k] * W2[k * 2 + j];
        out[b * 2 + j] = 1.0f / (1.0f + __expf(-z));
    }
}

// ---------------------------------------------------------------------------
extern "C" void kernel_launch(void* const* d_in, const int* in_sizes, int n_in,
                              void* d_out, int out_size, void* d_ws, size_t ws_size,
                              hipStream_t stream) {
    const float* x    = (const float*)d_in[0];
    const float* Wf_k = (const float*)d_in[1];
    const float* Wf_r = (const float*)d_in[2];
    const float* bf   = (const float*)d_in[3];
    const float* Wb_k = (const float*)d_in[4];
    const float* Wb_r = (const float*)d_in[5];
    const float* bb   = (const float*)d_in[6];
    const float* W1   = (const float*)d_in[7];
    const float* b1   = (const float*)d_in[8];
    const float* W2   = (const float*)d_in[9];
    const float* b2   = (const float*)d_in[10];
    float* out = (float*)d_out;

    char* ws = (char*)d_ws;
    const size_t OFF_XB   = 0;                        // 67,108,864 B
    const size_t OFF_WT   = 67108864;                 //  2,097,152 B
    const size_t OFF_HOUT = OFF_WT + 2097152;         //    131,072 B
    const size_t OFF_XP   = OFF_HOUT + 131072;        // 67,108,864 B (bf16)

    unsigned short* xb  = (unsigned short*)(ws + OFF_XB);
    unsigned short* wt  = (unsigned short*)(ws + OFF_WT);
    float*          ho  = (float*)(ws + OFF_HOUT);
    unsigned short* xpb = (unsigned short*)(ws + OFF_XP);

    conv_x<<<dim3(2048), dim3(256), 0, stream>>>(x, xb, 33554432 / 8);
    conv_wk<<<dim3(2048, 2), dim3(256), 0, stream>>>(Wf_k, Wb_k, wt);
    gemm_xp<<<dim3(256, 4, 2), dim3(256), 0, stream>>>(xb, wt, bf, bb, xpb);
    lstm_rec<<<dim3(256), dim3(512), 0, stream>>>(xpb, Wf_r, Wb_r, ho);
    mlp_head<<<dim3(128), dim3(64), 0, stream>>>(ho, W1, b1, W2, b2, out);
}

// Round 10
// 418.974 us; speedup vs baseline: 1.4479x; 1.0061x over previous
//
#include <hip/hip_runtime.h>
#include <cstdint>
#include <cstddef>

// ---------------------------------------------------------------------------
//   x:    [B=128, T=256, D=1024] fp32  ==  A[32768][1024] row-major (b*256+t)
//   Wk:   [1024, 512] per dir    Wr: [128, 512]    bias: [512]
//   xp[dir][t*128+b][512] = x[b,t,:] @ Wk + bias   (bf16, t-major, bias folded)
//   R10: conv_x FUSED into gemm_xp. A is reg-staged from fp32 x (float4 x2 ->
//   f2b x8 -> ds_write_b128 into the same XOR-swizzled slot); B stays on
//   global_load_lds. A-prefetch for kt+1 issued after B asyncs, waited with
//   counted vmcnt(8) + LITE_BARRIER (prefetch stays in flight across the
//   barrier). Removes conv_x (~35us), xb's 128MB of traffic, and halves the
//   workspace (136->69MB). Bit-identical numerics (same f2b -> same GEMM).
//   lstm_rec: reverted to R8's masked h-frag read (R9's replicated read
//   measured +2us). Everything else frozen.
// ---------------------------------------------------------------------------

typedef __attribute__((ext_vector_type(8))) short short8;
typedef __attribute__((ext_vector_type(4))) float f32x4;
typedef __attribute__((address_space(1))) unsigned int gas_uint;
typedef __attribute__((address_space(3))) unsigned int las_uint;
typedef __attribute__((address_space(1))) const unsigned short as1_us;

__device__ __forceinline__ unsigned short f2b(float f) {
    unsigned int u = __float_as_uint(f);
    u += 0x7FFFu + ((u >> 16) & 1u);          // RNE
    return (unsigned short)(u >> 16);
}
__device__ __forceinline__ float b2f(unsigned short u) {
    return __uint_as_float(((unsigned int)u) << 16);
}
// fast activations: v_rcp_f32 instead of exact fp32 division (~1 ulp)
__device__ __forceinline__ float rcp_(float x) { return __builtin_amdgcn_rcpf(x); }
__device__ __forceinline__ float sigmoidf_(float z) { return rcp_(1.0f + __expf(-z)); }
__device__ __forceinline__ float tanhf_(float z) {
    float e = __expf(2.0f * z);
    return 1.0f - 2.0f * rcp_(e + 1.0f);
}

// workgroup barrier WITHOUT the vmcnt(0) drain __syncthreads would emit:
// LDS ordering only — outstanding global prefetch loads stay in flight.
#define LITE_BARRIER() asm volatile("s_waitcnt lgkmcnt(0)\n\ts_barrier" ::: "memory")

// async global->LDS 16B
__device__ __forceinline__ void async_ld16(const unsigned short* g, unsigned short* l) {
    __builtin_amdgcn_global_load_lds(
        (gas_uint*)(uintptr_t)g,
        (las_uint*)(uintptr_t)(unsigned int)(uintptr_t)l,
        16, 0, 0);
}

// ---------------------------------------------------------------------------
// Kernel 1: transpose + convert Wk [1024][512] -> Wk_t [512][1024] bf16
// ---------------------------------------------------------------------------
__global__ void conv_wk(const float* __restrict__ wf, const float* __restrict__ wb,
                        unsigned short* __restrict__ wt) {
    int dir = blockIdx.y;
    const float* w = dir ? wb : wf;
    int id = blockIdx.x * blockDim.x + threadIdx.x;
    int g = id >> 10, d = id & 1023;
    wt[(size_t)dir * 524288 + id] = f2b(w[d * 512 + g]);
}

// ---------------------------------------------------------------------------
// Kernel 2: fused GEMM  xp = bf16(x) @ Wk_t^T + bias -> bf16 t-major
// 128x128 tile, BK=64. A reg-staged from fp32 x with in-register f2b and
// ds_write into the XOR-swizzled slot; B via global_load_lds w=16.
// Pipelined: B asyncs -> A-prefetch(kt+1) -> vmcnt(8) -> LITE_BARRIER, so
// the A prefetch overlaps the MFMA phase. XCD-aware tm grouping kept.
// ---------------------------------------------------------------------------
__global__ __launch_bounds__(256, 2) void gemm_xp(
    const float* __restrict__ X,              // [32768][1024] fp32
    const unsigned short* __restrict__ Wt,
    const float* __restrict__ bf_, const float* __restrict__ bb_,
    unsigned short* __restrict__ XP)
{
    __shared__ unsigned short As[128 * 64];
    __shared__ unsigned short Bs[128 * 64];

    const int tid  = threadIdx.x;

    // ---- XCD-aware decode (bijective: 2048 = 8 xcd * 256 steps) ----
    const int flat = blockIdx.x + 256 * (blockIdx.y + 4 * blockIdx.z);
    const int xcd  = flat & 7;
    const int p    = flat >> 3;
    const int tn   = p & 3;                  // fastest on an XCD
    const int dir  = (p >> 2) & 1;
    const int tm   = xcd * 32 + (p >> 3);    // 32 tms per XCD

    const int w    = tid >> 6;
    const int lane = tid & 63;
    const int lanelo = lane & 15;
    const int quad = lane >> 4;
    const int wm = w & 1, wn = w >> 1;

    const unsigned short* Bmat = Wt + (size_t)dir * 524288;
    const float* bias = dir ? bb_ : bf_;
    unsigned short* out = XP + (size_t)dir * 16777216;

    const float* gax[4];
    const unsigned short* gb[4];
    unsigned short* la[4];                   // per-lane explicit ds_write dest
    unsigned short* lb[4];                   // wave-uniform async dest
#pragma unroll
    for (int c = 0; c < 4; ++c) {
        int p2 = c * 256 + tid;
        int row = p2 >> 3;
        int lc = (p2 & 7) ^ (row & 7);
        gax[c] = X    + (size_t)(tm * 128 + row) * 1024 + lc * 8;
        gb[c]  = Bmat + (size_t)(tn * 128 + row) * 1024 + lc * 8;
        la[c]  = As + (size_t)p2 * 8;
        int ub = (c * 256 + (tid & ~63)) * 8;
        lb[c]  = Bs + ub;
    }

    // prologue: A fp32 prefetch for kt=0
    float4 xr[4][2];
#pragma unroll
    for (int c = 0; c < 4; ++c) {
        xr[c][0] = *(const float4*)(gax[c]);
        xr[c][1] = *(const float4*)(gax[c] + 4);
    }

    f32x4 acc[4][4];
#pragma unroll
    for (int i = 0; i < 4; i++)
#pragma unroll
        for (int j = 0; j < 4; j++) acc[i][j] = (f32x4){0.f, 0.f, 0.f, 0.f};

    for (int kt = 0; kt < 16; ++kt) {
        LITE_BARRIER();                      // WAR: prev iter's ds_reads done
        // stage A: convert prefetched regs -> bf16 -> swizzled LDS slot
#pragma unroll
        for (int c = 0; c < 4; ++c) {
            short8 s;
            s[0] = (short)f2b(xr[c][0].x); s[1] = (short)f2b(xr[c][0].y);
            s[2] = (short)f2b(xr[c][0].z); s[3] = (short)f2b(xr[c][0].w);
            s[4] = (short)f2b(xr[c][1].x); s[5] = (short)f2b(xr[c][1].y);
            s[6] = (short)f2b(xr[c][1].z); s[7] = (short)f2b(xr[c][1].w);
            *(short8*)la[c] = s;
        }
        // B async into LDS (vmcnt-tracked)
#pragma unroll
        for (int c = 0; c < 4; ++c) async_ld16(gb[c] + kt * 64, lb[c]);
        __builtin_amdgcn_sched_barrier(0);   // keep B asyncs ahead of A loads
        if (kt < 15) {
            // A fp32 prefetch for kt+1 — stays in flight across the barrier
#pragma unroll
            for (int c = 0; c < 4; ++c) {
                xr[c][0] = *(const float4*)(gax[c] + (kt + 1) * 64);
                xr[c][1] = *(const float4*)(gax[c] + (kt + 1) * 64 + 4);
            }
            __builtin_amdgcn_sched_barrier(0);
            asm volatile("s_waitcnt vmcnt(8)" ::: "memory");   // B done; 8 A loads fly
        } else {
            asm volatile("s_waitcnt vmcnt(0)" ::: "memory");   // last tile: drain B
        }
        LITE_BARRIER();                      // As ds_writes visible to all waves

#pragma unroll
        for (int ks = 0; ks < 2; ++ks) {
            short8 af[4], bfr[4];
#pragma unroll
            for (int i = 0; i < 4; ++i) {
                int row = wm * 64 + i * 16 + lanelo;
                af[i] = *(const short8*)(As + row * 64 + (((ks * 4 + quad) ^ (row & 7)) * 8));
            }
#pragma unroll
            for (int j = 0; j < 4; ++j) {
                int row = wn * 64 + j * 16 + lanelo;
                bfr[j] = *(const short8*)(Bs + row * 64 + (((ks * 4 + quad) ^ (row & 7)) * 8));
            }
#pragma unroll
            for (int i = 0; i < 4; ++i)
#pragma unroll
                for (int j = 0; j < 4; ++j)
                    acc[i][j] = __builtin_amdgcn_mfma_f32_16x16x32_bf16(af[i], bfr[j], acc[i][j], 0, 0, 0);
        }
    }

    float biasv[4];
#pragma unroll
    for (int j = 0; j < 4; ++j)
        biasv[j] = bias[tn * 128 + wn * 64 + j * 16 + lanelo];

#pragma unroll
    for (int i = 0; i < 4; ++i) {
#pragma unroll
        for (int r = 0; r < 4; ++r) {
            int gr = tm * 128 + wm * 64 + i * 16 + quad * 4 + r;   // = b*256 + t
            int bb = gr >> 8, tt = gr & 255;
            size_t orow = (size_t)(tt * 128 + bb) * 512;
#pragma unroll
            for (int j = 0; j < 4; ++j) {
                int col = tn * 128 + wn * 64 + j * 16 + lanelo;
                out[orow + col] = f2b(acc[i][j][r] + biasv[j]);
            }
        }
    }
}

// ---------------------------------------------------------------------------
// Kernel 3: LSTM recurrence. 256 blocks x 512 thr; block = (dir, seq).
// M=seq orientation (row 0 only real):  A = h [1 x 128], B = Wr [128 x 512].
// Wave w: 4 gate-tiles (N = g*128 + [16w,16w+16)) x 4 k-steps = 16 MFMAs.
// Quad-0 lanes hold z for all 4 gates of dim (16w+lanelo) in MFMA output
// regs -> activation in-lane (rcp-fast), h written as 1 b16 LDS store.
// One lite barrier per step. x prefetch depth 4. (R8 form, frozen.)
// ---------------------------------------------------------------------------
__global__ __launch_bounds__(512, 2) void lstm_rec(
    const unsigned short* __restrict__ XP,    // [2][256*128][512] bf16, bias folded
    const float* __restrict__ Wfr, const float* __restrict__ Wbr,
    float* __restrict__ Hout)                 // [2][128][128]
{
    __shared__ unsigned short h_lds[2][128];  // [buf][dim]

    const int tid    = threadIdx.x;
    const int w      = tid >> 6;              // 0..7
    const int lane   = tid & 63;
    const int lanelo = lane & 15;
    const int quad   = lane >> 4;
    const int dir    = blockIdx.x >> 7;
    const int seq    = blockIdx.x & 127;
    const int dim    = w * 16 + lanelo;       // 0..127

    const float* Wr = dir ? Wbr : Wfr;
    const unsigned short* xp = XP + (size_t)dir * 16777216;

    // --- one-time B-fragments: wrf[g][ks][j] = Wr[ks*32+quad*8+j][g*128+dim]
    short8 wrf[4][4];
#pragma unroll
    for (int g = 0; g < 4; ++g)
#pragma unroll
        for (int ks = 0; ks < 4; ++ks) {
            short8 f;
#pragma unroll
            for (int j = 0; j < 8; ++j)
                f[j] = (short)f2b(Wr[(size_t)(ks * 32 + quad * 8 + j) * 512 + g * 128 + dim]);
            wrf[g][ks] = f;
        }

    if (tid < 128) ((unsigned short*)h_lds)[tid] = 0;   // zero h buffer 0

    // A-fragment of h; only row 0 (lanelo==0 lanes) is real.
    short8 hfrag[4];
    const short8 hz = (short8){0, 0, 0, 0, 0, 0, 0, 0};
#pragma unroll
    for (int ks = 0; ks < 4; ++ks) hfrag[ks] = hz;

    float cv = 0.f, hv = 0.f;

    // x prefetch: explicit address_space(1) loads (vmcnt-only, immune to the
    // lgkmcnt drain in LITE_BARRIER). Depth 4: consume buf, re-load for t+4.
    const ptrdiff_t xstep = dir ? -65536 : 65536;       // elements per t
    const unsigned short* xb_ =
        xp + (size_t)(dir ? 255 : 0) * 65536 + (size_t)seq * 512 + dim;

    unsigned int xA[4], xB[4], xC[4], xD[4];

#define XLOAD(BUF)                                                               \
    {                                                                            \
        const as1_us* xg = (const as1_us*)(uintptr_t)xb_;                        \
        _Pragma("unroll")                                                        \
        for (int g = 0; g < 4; ++g) BUF[g] = xg[g * 128];                        \
        xb_ += xstep;                                                            \
    }

    XLOAD(xA)   // t=0
    XLOAD(xB)   // t=1
    XLOAD(xC)   // t=2
    XLOAD(xD)   // t=3
    // overshoot past the sequence end stays inside the XP allocation
    // (reads the other direction's region; values unused).

    LITE_BARRIER();                           // h_lds[0] zeros visible

    const f32x4 kZ = (f32x4){0.f, 0.f, 0.f, 0.f};

#define LSTM_STEP(XC_, CUR, NXT)                                                 \
    {                                                                            \
        /* consume x loaded 4 steps ago (long arrived); reissue for t+4 */       \
        float xv0 = b2f((unsigned short)XC_[0]);                                 \
        float xv1 = b2f((unsigned short)XC_[1]);                                 \
        float xv2 = b2f((unsigned short)XC_[2]);                                 \
        float xv3 = b2f((unsigned short)XC_[3]);                                 \
        XLOAD(XC_)                                                               \
        /* masked A-frag read: only row 0 is real */                             \
        if (lanelo == 0) {                                                       \
            _Pragma("unroll")                                                    \
            for (int ks = 0; ks < 4; ++ks)                                       \
                hfrag[ks] = *(const short8*)(&h_lds[CUR][ks * 32 + quad * 8]);   \
        }                                                                        \
        /* 16 MFMAs: 4 independent gate chains, depth 4 */                       \
        f32x4 z0 = __builtin_amdgcn_mfma_f32_16x16x32_bf16(hfrag[0], wrf[0][0], kZ, 0, 0, 0); \
        f32x4 z1 = __builtin_amdgcn_mfma_f32_16x16x32_bf16(hfrag[0], wrf[1][0], kZ, 0, 0, 0); \
        f32x4 z2 = __builtin_amdgcn_mfma_f32_16x16x32_bf16(hfrag[0], wrf[2][0], kZ, 0, 0, 0); \
        f32x4 z3 = __builtin_amdgcn_mfma_f32_16x16x32_bf16(hfrag[0], wrf[3][0], kZ, 0, 0, 0); \
        _Pragma("unroll")                                                        \
        for (int ks = 1; ks < 4; ++ks) {                                         \
            z0 = __builtin_amdgcn_mfma_f32_16x16x32_bf16(hfrag[ks], wrf[0][ks], z0, 0, 0, 0); \
            z1 = __builtin_amdgcn_mfma_f32_16x16x32_bf16(hfrag[ks], wrf[1][ks], z1, 0, 0, 0); \
            z2 = __builtin_amdgcn_mfma_f32_16x16x32_bf16(hfrag[ks], wrf[2][ks], z2, 0, 0, 0); \
            z3 = __builtin_amdgcn_mfma_f32_16x16x32_bf16(hfrag[ks], wrf[3][ks], z3, 0, 0, 0); \
        }                                                                        \
        /* activation: quad-0 lanes own (dim); all gates in-lane */              \
        if (quad == 0) {                                                         \
            float zi = z0[0] + xv0, zf = z1[0] + xv1;                            \
            float zg = z2[0] + xv2, zo = z3[0] + xv3;                            \
            float iv = sigmoidf_(zi), fv = sigmoidf_(zf);                        \
            float gv = tanhf_(zg),    ov = sigmoidf_(zo);                        \
            cv = fv * cv + iv * gv;                                              \
            hv = ov * tanhf_(cv);                                                \
            h_lds[NXT][dim] = f2b(hv);                                           \
        }                                                                        \
        LITE_BARRIER();                                                          \
    }

    for (int t = 0; t < 256; t += 4) {
        LSTM_STEP(xA, 0, 1)
        LSTM_STEP(xB, 1, 0)
        LSTM_STEP(xC, 0, 1)
        LSTM_STEP(xD, 1, 0)
    }
#undef LSTM_STEP
#undef XLOAD

    if (quad == 0)
        Hout[(size_t)(dir * 128 + seq) * 128 + dim] = hv;
}

// ---------------------------------------------------------------------------
// Kernel 4: MLP head
// ---------------------------------------------------------------------------
__global__ void mlp_head(const float* __restrict__ Hout,
                         const float* __restrict__ W1, const float* __restrict__ b1,
                         const float* __restrict__ W2, const float* __restrict__ b2,
                         float* __restrict__ out)
{
    __shared__ float y1[32];
    int b = blockIdx.x;
    int j = threadIdx.x;
    const float* hf = Hout + (size_t)b * 128;
    const float* hb = Hout + (size_t)(128 + b) * 128;
    if (j < 32) {
        float acc = b1[j];
        for (int k = 0; k < 128; ++k) acc += hf[k] * W1[k * 32 + j];
        for (int k = 0; k < 128; ++k) acc += hb[k] * W1[(128 + k) * 32 + j];
        y1[j] = fmaxf(acc, 0.0f);
    }
    __syncthreads();
    if (j < 2) {
        float z = b2[j];
        for (int k = 0; k < 32; ++k) z += y1[k] * W2[k * 2 + j];
        out[b * 2 + j] = 1.0f / (1.0f + __expf(-z));
    }
}

// ---------------------------------------------------------------------------
extern "C" void kernel_launch(void* const* d_in, const int* in_sizes, int n_in,
                              void* d_out, int out_size, void* d_ws, size_t ws_size,
                              hipStream_t stream) {
    const float* x    = (const float*)d_in[0];
    const float* Wf_k = (const float*)d_in[1];
    const float* Wf_r = (const float*)d_in[2];
    const float* bf   = (const float*)d_in[3];
    const float* Wb_k = (const float*)d_in[4];
    const float* Wb_r = (const float*)d_in[5];
    const float* bb   = (const float*)d_in[6];
    const float* W1   = (const float*)d_in[7];
    const float* b1   = (const float*)d_in[8];
    const float* W2   = (const float*)d_in[9];
    const float* b2   = (const float*)d_in[10];
    float* out = (float*)d_out;

    char* ws = (char*)d_ws;
    const size_t OFF_WT   = 0;                        //  2,097,152 B
    const size_t OFF_HOUT = 2097152;                  //    131,072 B
    const size_t OFF_XP   = OFF_HOUT + 131072;        // 67,108,864 B (bf16)
    // total workspace: ~69.3 MB (was 136.4 MB)

    unsigned short* wt  = (unsigned short*)(ws + OFF_WT);
    float*          ho  = (float*)(ws + OFF_HOUT);
    unsigned short* xpb = (unsigned short*)(ws + OFF_XP);

    conv_wk<<<dim3(2048, 2), dim3(256), 0, stream>>>(Wf_k, Wb_k, wt);
    gemm_xp<<<dim3(256, 4, 2), dim3(256), 0, stream>>>(x, wt, bf, bb, xpb);
    lstm_rec<<<dim3(256), dim3(512), 0, stream>>>(xpb, Wf_r, Wb_r, ho);
    mlp_head<<<dim3(128), dim3(64), 0, stream>>>(ho, W1, b1, W2, b2, out);
}